// Round 7
// baseline (244.029 us; speedup 1.0000x reference)
//
#include <hip/hip_runtime.h>
#include <hip/hip_bf16.h>
#include <math.h>

#define NN    2048
#define NE    32768
#define NP    262144
#define CS_   384
#define CZ_   128
#define CG_   16
#define NRBF_ 64

typedef __attribute__((ext_vector_type(8))) short bf16x8;
typedef __attribute__((ext_vector_type(4))) float f32x4;

__device__ __forceinline__ unsigned short f2bf(float f) {
  __hip_bfloat16 h = __float2bfloat16(f);
  union { __hip_bfloat16 h; unsigned short u; } cv; cv.h = h; return cv.u;
}
__device__ __forceinline__ float bfbits(unsigned short h) {
  return __uint_as_float((unsigned)h << 16);
}
__device__ __forceinline__ float sigf(float x) {
  return __builtin_amdgcn_rcpf(1.f + __expf(-x));
}

// ---------------- K1: node projections -> bf16 rows ----------------
__global__ void k_nodeproj(const float* __restrict__ nf,
                           const float* __restrict__ wnl, const float* __restrict__ bnl,
                           const float* __restrict__ wnr, const float* __restrict__ bnr,
                           unsigned short* __restrict__ nl, unsigned short* __restrict__ nr) {
  const int n = blockIdx.x;
  const int t = threadIdx.x;
  if (t >= 32) return;
  const float* __restrict__ w = (t < 16) ? wnl : wnr;
  const int col = t & 15;
  const float* __restrict__ row = nf + (size_t)n * CS_;
  float acc = 0.f;
  #pragma unroll 8
  for (int k = 0; k < CS_; ++k) acc = fmaf(row[k], w[k * CG_ + col], acc);
  acc += (t < 16) ? bnl[col] : bnr[col];
  ((t < 16) ? nl : nr)[n * CG_ + col] = f2bf(acc);
}

// ---------------- K_prep: weights -> MFMA-frag-ready bf16 (hi + lo residual) ----------------
// shorts layout:
//   [0,32768)         w_dg hi
//   [32768,40960)     w_dp hi
//   [40960,106496)    w_eg,w_ep,w_lo,w_og HI (16384 each)
//   [106496,172032)   same four, LO residual (hi_ptr + 65536)
//   [172032,180224)   w_dp LO residual
__global__ void k_prep(const float* __restrict__ wdg, const float* __restrict__ wdp,
                       const float* __restrict__ weg, const float* __restrict__ wep,
                       const float* __restrict__ wlo, const float* __restrict__ wog,
                       unsigned short* __restrict__ frag) {
  const int idx = blockIdx.x * 256 + threadIdx.x;
  if (idx >= 180224) return;
  if (idx < 32768) {
    const int e = idx & 7, l = (idx >> 3) & 63, ks = (idx >> 9) & 7, n = idx >> 12;
    frag[idx] = f2bf(wdg[(size_t)(ks * 32 + (l >> 4) * 8 + e) * CZ_ + n * 16 + (l & 15)]);
  } else if (idx < 40960) {
    const int j = idx - 32768;
    const int e = j & 7, l = (j >> 3) & 63, ks2 = (j >> 9) & 1, n = j >> 10;
    frag[idx] = f2bf(wdp[(size_t)(ks2 * 32 + (l >> 4) * 8 + e) * CZ_ + n * 16 + (l & 15)]);
  } else if (idx < 172032) {
    const bool lo = idx >= 106496;
    const int j2 = (idx - 40960) & 65535;
    const int m = j2 >> 14;
    const float* __restrict__ mp = (m == 0) ? weg : (m == 1) ? wep : (m == 2) ? wlo : wog;
    const int j = j2 & 16383;
    const int e = j & 7, l = (j >> 3) & 63, ks = (j >> 9) & 3, n = j >> 11;
    const float v = mp[(size_t)(ks * 32 + (l >> 4) * 8 + e) * CZ_ + n * 16 + (l & 15)];
    const unsigned short h = f2bf(v);
    frag[idx] = lo ? f2bf(v - bfbits(h)) : h;
  } else {
    const int j = idx - 172032;
    const int e = j & 7, l = (j >> 3) & 63, ks2 = (j >> 9) & 1, n = j >> 10;
    const float v = wdp[(size_t)(ks2 * 32 + (l >> 4) * 8 + e) * CZ_ + n * 16 + (l & 15)];
    const unsigned short h = f2bf(v);
    frag[idx] = f2bf(v - bfbits(h));
  }
}

// ---------------- sort machinery ----------------
__global__ void k_hist(const int* __restrict__ ee, int* __restrict__ hist) {
  const int p = blockIdx.x * 256 + threadIdx.x;
  atomicAdd(&hist[ee[p]], 1);
}

// computes exclusive-scan starts AND zeroes hist (so k_scatter can reuse it as cursor)
__global__ __launch_bounds__(1024) void k_scan(int* __restrict__ hist,
                                               int* __restrict__ start) {
  __shared__ int tot[1024];
  const int t = threadIdx.x;
  const int base = t * 32;
  int s = 0;
  for (int k = 0; k < 32; ++k) s += hist[base + k];
  tot[t] = s;
  __syncthreads();
  for (int off = 1; off < 1024; off <<= 1) {
    int v = tot[t];
    int u = (t >= off) ? tot[t - off] : 0;
    __syncthreads();
    tot[t] = v + u;
    __syncthreads();
  }
  int run = (t == 0) ? 0 : tot[t - 1];
  for (int k = 0; k < 32; ++k) {
    const int h = hist[base + k];
    start[base + k] = run;
    run += h;
    hist[base + k] = 0;   // each hist element owned by exactly this thread
  }
  if (t == 1023) start[32768] = run;
}

__global__ void k_scatter(const int* __restrict__ ee, const int* __restrict__ start,
                          int* __restrict__ cursor, int* __restrict__ perm) {
  const int p = blockIdx.x * 256 + threadIdx.x;
  const int e = ee[p];
  const int idx = atomicAdd(&cursor[e], 1);
  perm[start[e] + idx] = p;
}

// ---------------- LN -> split bf16 A-fragments (hi + lo) in frag-linear LDS ----------------
__device__ __forceinline__ void ln_to_frag2(
    const float* __restrict__ src, const float* __restrict__ gam,
    const float* __restrict__ bet, int row0, int tid,
    unsigned short (* __restrict__ afh)[64][8],
    unsigned short (* __restrict__ afl)[64][8]) {
  const int r = tid >> 2, qt = tid & 3;
  const float* __restrict__ xp = src + (size_t)(row0 + r) * CZ_ + qt * 32;
  float v[32];
  #pragma unroll
  for (int j = 0; j < 8; ++j) {
    const float4 t4 = ((const float4*)xp)[j];
    v[4*j+0] = t4.x; v[4*j+1] = t4.y; v[4*j+2] = t4.z; v[4*j+3] = t4.w;
  }
  float sum = 0.f, sq = 0.f;
  #pragma unroll
  for (int q = 0; q < 32; ++q) { sum += v[q]; sq = fmaf(v[q], v[q], sq); }
  sum += __shfl_xor(sum, 1); sq += __shfl_xor(sq, 1);
  sum += __shfl_xor(sum, 2); sq += __shfl_xor(sq, 2);
  const float mean = sum * (1.f / CZ_);
  const float rstd = rsqrtf(sq * (1.f / CZ_) - mean * mean + 1e-5f);
  const int fb = (r >> 4) * 4 + qt;
  const int r15 = r & 15;
  #pragma unroll
  for (int g = 0; g < 4; ++g) {
    unsigned pkh[4], pkl[4];
    #pragma unroll
    for (int h2 = 0; h2 < 4; ++h2) {
      const int c0 = qt * 32 + g * 8 + 2 * h2;
      const float f0 = (v[g*8+2*h2]   - mean) * rstd * gam[c0]   + bet[c0];
      const float f1 = (v[g*8+2*h2+1] - mean) * rstd * gam[c0+1] + bet[c0+1];
      const unsigned short h0 = f2bf(f0), h1 = f2bf(f1);
      const unsigned short l0 = f2bf(f0 - bfbits(h0)), l1 = f2bf(f1 - bfbits(h1));
      pkh[h2] = (unsigned)h0 | ((unsigned)h1 << 16);
      pkl[h2] = (unsigned)l0 | ((unsigned)l1 << 16);
    }
    *(uint4*)&afh[fb][g * 16 + r15][0] = make_uint4(pkh[0], pkh[1], pkh[2], pkh[3]);
    *(uint4*)&afl[fb][g * 16 + r15][0] = make_uint4(pkl[0], pkl[1], pkl[2], pkl[3]);
  }
}

// ------- K2: edge2 = sigmoid(LN(src)@w_eg+b_eg) * (LN(src)@w_ep+b_ep) -> d_out scratch -------
__global__ __launch_bounds__(256) void k_edge2_mfma(
    const float* __restrict__ sef,
    const float* __restrict__ gs, const float* __restrict__ bs,
    const unsigned short* __restrict__ wf,   // HI: w_eg at 0, w_ep at +16384; LO at +65536
    const float* __restrict__ beg, const float* __restrict__ bep,
    float* __restrict__ e2) {
  __shared__ unsigned short afh[16][64][8];
  __shared__ unsigned short afl[16][64][8];
  const int tid = threadIdx.x;
  const int row0 = blockIdx.x * 64;
  ln_to_frag2(sef, gs, bs, row0, tid, afh, afl);
  __syncthreads();

  const int lane = tid & 63;
  const int w = tid >> 6;
  f32x4 c1[8], c2[8];
  #pragma unroll
  for (int n = 0; n < 8; ++n) { c1[n] = (f32x4)0.f; c2[n] = (f32x4)0.f; }
  #pragma unroll
  for (int ks = 0; ks < 4; ++ks) {
    const bf16x8 ah = *(const bf16x8*)&afh[w * 4 + ks][lane][0];
    const bf16x8 al = *(const bf16x8*)&afl[w * 4 + ks][lane][0];
    #pragma unroll
    for (int n = 0; n < 8; ++n) {
      const size_t bo = ((size_t)((n * 4 + ks) * 64 + lane)) * 8;
      const bf16x8 b1h = *(const bf16x8*)(wf + bo);
      const bf16x8 b1l = *(const bf16x8*)(wf + 65536 + bo);
      const bf16x8 b2h = *(const bf16x8*)(wf + 16384 + bo);
      const bf16x8 b2l = *(const bf16x8*)(wf + 81920 + bo);
      c1[n] = __builtin_amdgcn_mfma_f32_16x16x32_bf16(ah, b1h, c1[n], 0, 0, 0);
      c1[n] = __builtin_amdgcn_mfma_f32_16x16x32_bf16(al, b1h, c1[n], 0, 0, 0);
      c1[n] = __builtin_amdgcn_mfma_f32_16x16x32_bf16(ah, b1l, c1[n], 0, 0, 0);
      c2[n] = __builtin_amdgcn_mfma_f32_16x16x32_bf16(ah, b2h, c2[n], 0, 0, 0);
      c2[n] = __builtin_amdgcn_mfma_f32_16x16x32_bf16(al, b2h, c2[n], 0, 0, 0);
      c2[n] = __builtin_amdgcn_mfma_f32_16x16x32_bf16(ah, b2l, c2[n], 0, 0, 0);
    }
  }
  const int c15 = lane & 15, rq = lane >> 4;
  #pragma unroll
  for (int n = 0; n < 8; ++n) {
    const int ch = n * 16 + c15;
    const float bg = beg[ch], bp = bep[ch];
    #pragma unroll
    for (int r = 0; r < 4; ++r) {
      const int row = row0 + w * 16 + rq * 4 + r;
      e2[(size_t)row * CZ_ + ch] = sigf(c1[n][r] + bg) * (c2[n][r] + bp);
    }
  }
}

// ------- K3: MFMA pair features for channel-half CC (f32 out, [NP,64]) -------
template <int CC>
__global__ __launch_bounds__(256, 2) void k_pairfeat(
    const int* __restrict__ ee,
    const int* __restrict__ sei, const int* __restrict__ dei,
    const unsigned short* __restrict__ nlb, const unsigned short* __restrict__ nrb,
    const float* __restrict__ trans, const unsigned short* __restrict__ frag,
    const float* __restrict__ bdg, const float* __restrict__ bdp,
    float* __restrict__ feat) {
  __shared__ unsigned short sfrag[20480];  // 32KB gate Bfrag half + 8KB rbf hi half
  const int tid = threadIdx.x;

  {
    const unsigned short* __restrict__ gsrc = frag + CC * 16384;
    #pragma unroll
    for (int i = 0; i < 8; ++i)
      ((float4*)sfrag)[i * 256 + tid] = ((const float4*)gsrc)[i * 256 + tid];
    const unsigned short* __restrict__ rsrc = frag + 32768 + CC * 4096;
    #pragma unroll
    for (int i = 0; i < 2; ++i)
      ((float4*)(sfrag + 16384))[i * 256 + tid] = ((const float4*)rsrc)[i * 256 + tid];
  }
  const unsigned short* __restrict__ wf2l = frag + 172032 + CC * 4096;  // rbf LO (global, L1)

  const int lane = tid & 63;
  const int w = tid >> 6;
  const int g = lane >> 4;
  const int c15 = lane & 15;
  const int rowbase = blockIdx.x * 128 + w * 32;

  unsigned int nlu[2][8], nru[2][8];
  float dist[2];
  #pragma unroll
  for (int m = 0; m < 2; ++m) {
    const int p = rowbase + m * 16 + c15;   // natural order: coalesced index loads
    const int e0 = ee[p];
    const int e1 = ee[NP + p];
    const int n1 = sei[e1];
    const int n2 = dei[e0];
    const uint4 a = ((const uint4*)(nlb + (size_t)n1 * CG_))[0];
    const uint4 b = ((const uint4*)(nlb + (size_t)n1 * CG_))[1];
    nlu[m][0]=a.x; nlu[m][1]=a.y; nlu[m][2]=a.z; nlu[m][3]=a.w;
    nlu[m][4]=b.x; nlu[m][5]=b.y; nlu[m][6]=b.z; nlu[m][7]=b.w;
    const uint4 c = ((const uint4*)(nrb + (size_t)n2 * CG_))[0];
    const uint4 d = ((const uint4*)(nrb + (size_t)n2 * CG_))[1];
    nru[m][0]=c.x; nru[m][1]=c.y; nru[m][2]=c.z; nru[m][3]=c.w;
    nru[m][4]=d.x; nru[m][5]=d.y; nru[m][6]=d.z; nru[m][7]=d.w;
    const float dx = trans[n1*3+0] - trans[n2*3+0] + 1e-8f;
    const float dy = trans[n1*3+1] - trans[n2*3+1] + 1e-8f;
    const float dz = trans[n1*3+2] - trans[n2*3+2] + 1e-8f;
    dist[m] = sqrtf(fmaf(dx, dx, fmaf(dy, dy, dz * dz)));
  }
  __syncthreads();

  f32x4 acc[2][4], acc2[2][4];
  #pragma unroll
  for (int m = 0; m < 2; ++m)
    #pragma unroll
    for (int n = 0; n < 4; ++n) { acc[m][n] = (f32x4)0.f; acc2[m][n] = (f32x4)0.f; }

  const bool hiI = (lane & 32) != 0;
  const bool hiJ = (lane & 16) != 0;

  // gate GEMM: K=256 (single-bf16: sigmoid compresses error 4x)
  #pragma unroll
  for (int ks = 0; ks < 8; ++ks) {
    bf16x8 af[2];
    #pragma unroll
    for (int m = 0; m < 2; ++m) {
      const unsigned wv = nlu[m][ks];
      const float nli = __uint_as_float(hiI ? (wv & 0xFFFF0000u) : (wv << 16));
      #pragma unroll
      for (int ep = 0; ep < 4; ++ep) {
        const unsigned wr = hiJ ? nru[m][4 + ep] : nru[m][ep];
        const float j0 = __uint_as_float(wr << 16);
        const float j1 = __uint_as_float(wr & 0xFFFF0000u);
        af[m][2*ep]   = (short)f2bf(nli * j0);
        af[m][2*ep+1] = (short)f2bf(nli * j1);
      }
    }
    #pragma unroll
    for (int n = 0; n < 4; ++n) {
      const bf16x8 bf = *(const bf16x8*)(sfrag + ((size_t)((n * 8 + ks) * 64 + lane)) * 8);
      acc[0][n] = __builtin_amdgcn_mfma_f32_16x16x32_bf16(af[0], bf, acc[0][n], 0, 0, 0);
      acc[1][n] = __builtin_amdgcn_mfma_f32_16x16x32_bf16(af[1], bf, acc[1][n], 0, 0, 0);
    }
  }

  // RBF GEMM: K=64, split-bf16 (exp hi+lo, w_dp hi+lo)
  const float MU_STEP = 20.f / 63.f;
  const float INV_SIG = 64.f / 20.f;
  #pragma unroll
  for (int ks2 = 0; ks2 < 2; ++ks2) {
    bf16x8 a2h[2], a2l[2];
    const int k2b = ks2 * 32 + g * 8;
    #pragma unroll
    for (int m = 0; m < 2; ++m) {
      #pragma unroll
      for (int e = 0; e < 8; ++e) {
        const float mu = (float)(k2b + e) * MU_STEP;
        const float u = (dist[m] - mu) * INV_SIG;
        const float ev = __expf(-u * u);
        const unsigned short h = f2bf(ev);
        a2h[m][e] = (short)h;
        a2l[m][e] = (short)f2bf(ev - bfbits(h));
      }
    }
    #pragma unroll
    for (int n = 0; n < 4; ++n) {
      const size_t bo = ((size_t)((n * 2 + ks2) * 64 + lane)) * 8;
      const bf16x8 b2h = *(const bf16x8*)(sfrag + 16384 + bo);
      const bf16x8 b2l = *(const bf16x8*)(wf2l + bo);
      acc2[0][n] = __builtin_amdgcn_mfma_f32_16x16x32_bf16(a2h[0], b2h, acc2[0][n], 0, 0, 0);
      acc2[0][n] = __builtin_amdgcn_mfma_f32_16x16x32_bf16(a2l[0], b2h, acc2[0][n], 0, 0, 0);
      acc2[0][n] = __builtin_amdgcn_mfma_f32_16x16x32_bf16(a2h[0], b2l, acc2[0][n], 0, 0, 0);
      acc2[1][n] = __builtin_amdgcn_mfma_f32_16x16x32_bf16(a2h[1], b2h, acc2[1][n], 0, 0, 0);
      acc2[1][n] = __builtin_amdgcn_mfma_f32_16x16x32_bf16(a2l[1], b2h, acc2[1][n], 0, 0, 0);
      acc2[1][n] = __builtin_amdgcn_mfma_f32_16x16x32_bf16(a2h[1], b2l, acc2[1][n], 0, 0, 0);
    }
  }

  float bdgv[4], bdpv[4];
  #pragma unroll
  for (int n = 0; n < 4; ++n) {
    bdgv[n] = bdg[(CC * 4 + n) * 16 + c15];
    bdpv[n] = bdp[(CC * 4 + n) * 16 + c15];
  }

  #pragma unroll
  for (int m = 0; m < 2; ++m) {
    #pragma unroll
    for (int n = 0; n < 4; ++n) {
      #pragma unroll
      for (int r = 0; r < 4; ++r) {
        const float gv = sigf(acc[m][n][r] + bdgv[n]);
        const int row = rowbase + m * 16 + g * 4 + r;
        feat[(size_t)row * 64 + n * 16 + c15] = gv * (acc2[m][n][r] + bdpv[n]);
      }
    }
  }
}

// ------- K_segsum: per-edge canonical (p-sorted) gather-sum over a 64-ch half -------
// Output depends only on the SET of pair ids per segment -> deterministic across calls.
__global__ __launch_bounds__(64) void k_segsum(
    const int* __restrict__ start, const int* __restrict__ perm,
    const float* __restrict__ feat, float* __restrict__ e2, int cc) {
  __shared__ int lst[512];
  const int e = blockIdx.x;
  const int t = threadIdx.x;
  const int s0 = start[e], s1 = start[e + 1];
  const int deg = s1 - s0;
  float s = 0.f;
  if (deg <= 512) {
    for (int i = t; i < deg; i += 64) lst[i] = perm[s0 + i];
    __syncthreads();
    if (t == 0) {
      for (int a = 1; a < deg; ++a) {
        const int v = lst[a];
        int b = a - 1;
        while (b >= 0 && lst[b] > v) { lst[b + 1] = lst[b]; --b; }
        lst[b + 1] = v;
      }
    }
    __syncthreads();
    for (int j = 0; j < deg; ++j)
      s += feat[(size_t)lst[j] * 64 + t];
  } else {  // unreachable at this scale; canonical selection-scan keeps determinism anyway
    int last = -1;
    for (int j = 0; j < deg; ++j) {
      int mn = 0x7fffffff;
      for (int i = 0; i < deg; ++i) {
        const int p = perm[s0 + i];
        if (p > last && p < mn) mn = p;
      }
      last = mn;
      s += feat[(size_t)mn * 64 + t];
    }
  }
  float* __restrict__ dst = e2 + (size_t)e * CZ_ + cc * 64 + t;
  *dst = s * (*dst);
}

// ------- K4: out = (LN(prod)@w_lo+b_lo) * sigmoid(LN(dst)@w_og+b_og), split MFMA -------
// prod and out are the SAME buffer (d_out): each block reads only its own 64 rows
// (in ln_to_frag2, before the barrier) and writes only those rows afterwards.
__global__ __launch_bounds__(256) void k_final_mfma(
    float* po, const float* __restrict__ def,
    const float* __restrict__ go, const float* __restrict__ bo,
    const float* __restrict__ gd, const float* __restrict__ bd,
    const unsigned short* __restrict__ wf,   // HI: w_lo at 0, w_og at +16384; LO at +65536
    const float* __restrict__ blo, const float* __restrict__ bog) {
  __shared__ unsigned short af1h[16][64][8];
  __shared__ unsigned short af1l[16][64][8];
  __shared__ unsigned short af2h[16][64][8];
  __shared__ unsigned short af2l[16][64][8];
  const int tid = threadIdx.x;
  const int row0 = blockIdx.x * 64;
  ln_to_frag2(po, go, bo, row0, tid, af1h, af1l);
  ln_to_frag2(def, gd, bd, row0, tid, af2h, af2l);
  __syncthreads();

  const int lane = tid & 63;
  const int w = tid >> 6;
  f32x4 c1[8], c2[8];
  #pragma unroll
  for (int n = 0; n < 8; ++n) { c1[n] = (f32x4)0.f; c2[n] = (f32x4)0.f; }
  #pragma unroll
  for (int ks = 0; ks < 4; ++ks) {
    const bf16x8 a1h = *(const bf16x8*)&af1h[w * 4 + ks][lane][0];
    const bf16x8 a1l = *(const bf16x8*)&af1l[w * 4 + ks][lane][0];
    const bf16x8 a2h = *(const bf16x8*)&af2h[w * 4 + ks][lane][0];
    const bf16x8 a2l = *(const bf16x8*)&af2l[w * 4 + ks][lane][0];
    #pragma unroll
    for (int n = 0; n < 8; ++n) {
      const size_t bo = ((size_t)((n * 4 + ks) * 64 + lane)) * 8;
      const bf16x8 b1h = *(const bf16x8*)(wf + bo);
      const bf16x8 b1l = *(const bf16x8*)(wf + 65536 + bo);
      const bf16x8 b2h = *(const bf16x8*)(wf + 16384 + bo);
      const bf16x8 b2l = *(const bf16x8*)(wf + 81920 + bo);
      c1[n] = __builtin_amdgcn_mfma_f32_16x16x32_bf16(a1h, b1h, c1[n], 0, 0, 0);
      c1[n] = __builtin_amdgcn_mfma_f32_16x16x32_bf16(a1l, b1h, c1[n], 0, 0, 0);
      c1[n] = __builtin_amdgcn_mfma_f32_16x16x32_bf16(a1h, b1l, c1[n], 0, 0, 0);
      c2[n] = __builtin_amdgcn_mfma_f32_16x16x32_bf16(a2h, b2h, c2[n], 0, 0, 0);
      c2[n] = __builtin_amdgcn_mfma_f32_16x16x32_bf16(a2l, b2h, c2[n], 0, 0, 0);
      c2[n] = __builtin_amdgcn_mfma_f32_16x16x32_bf16(a2h, b2l, c2[n], 0, 0, 0);
    }
  }
  const int c15 = lane & 15, rq = lane >> 4;
  #pragma unroll
  for (int n = 0; n < 8; ++n) {
    const int ch = n * 16 + c15;
    const float bl = blo[ch], bg = bog[ch];
    #pragma unroll
    for (int r = 0; r < 4; ++r) {
      const int row = row0 + w * 16 + rq * 4 + r;
      po[(size_t)row * CZ_ + ch] = (c1[n][r] + bl) * sigf(c2[n][r] + bg);
    }
  }
}

extern "C" void kernel_launch(void* const* d_in, const int* in_sizes, int n_in,
                              void* d_out, int out_size, void* d_ws, size_t ws_size,
                              hipStream_t stream) {
  const float* nf     = (const float*)d_in[0];
  const float* trans  = (const float*)d_in[1];
  const float* dst_ef = (const float*)d_in[2];
  const int*   dst_ei = (const int*)d_in[3];
  const float* src_ef = (const float*)d_in[4];
  const int*   src_ei = (const int*)d_in[5];
  const int*   ee     = (const int*)d_in[6];
  const float* w_nl  = (const float*)d_in[7];  const float* b_nl  = (const float*)d_in[8];
  const float* w_nr  = (const float*)d_in[9];  const float* b_nr  = (const float*)d_in[10];
  const float* g_dst = (const float*)d_in[11]; const float* bt_dst= (const float*)d_in[12];
  const float* g_src = (const float*)d_in[13]; const float* bt_src= (const float*)d_in[14];
  const float* w_ep  = (const float*)d_in[15]; const float* b_ep  = (const float*)d_in[16];
  const float* w_eg  = (const float*)d_in[17]; const float* b_eg  = (const float*)d_in[18];
  const float* w_dg  = (const float*)d_in[19]; const float* b_dg  = (const float*)d_in[20];
  const float* w_dp  = (const float*)d_in[21]; const float* b_dp  = (const float*)d_in[22];
  const float* g_out = (const float*)d_in[23]; const float* bt_out= (const float*)d_in[24];
  const float* w_lo  = (const float*)d_in[25]; const float* b_lo  = (const float*)d_in[26];
  const float* w_og  = (const float*)d_in[27]; const float* b_og  = (const float*)d_in[28];

  float* e2 = (float*)d_out;   // d_out doubles as edge2/prod scratch until k_final

  char* ws = (char*)d_ws;
  size_t off = 0;
  float*        feat = (float*)(ws + off);        off += (size_t)NP * 64 * 4;   // 67.1MB
  unsigned short* nlb = (unsigned short*)(ws + off); off += (size_t)NN * CG_ * 2;
  unsigned short* nrb = (unsigned short*)(ws + off); off += (size_t)NN * CG_ * 2;
  unsigned short* frag = (unsigned short*)(ws + off); off += 180224 * 2;        // 352KB
  int* hist  = (int*)(ws + off); off += 32768 * 4;   // reused as scatter cursor
  int* start = (int*)(ws + off); off += 32772 * 4;
  int* perm  = (int*)(ws + off); off += (size_t)NP * 4;
  // total ~68.9MB

  const unsigned short* wf_pair = frag;                  // w_dg + w_dp frags (+ w_dp lo @172032)
  const unsigned short* wf_e2   = frag + 40960;          // w_eg/w_ep hi (lo at +65536)
  const unsigned short* wf_fin  = frag + 40960 + 32768;  // w_lo/w_og hi (lo at +65536)

  hipMemsetAsync(hist, 0, 32768 * 4, stream);

  k_nodeproj<<<NN, 64, 0, stream>>>(nf, w_nl, b_nl, w_nr, b_nr, nlb, nrb);
  k_prep<<<704, 256, 0, stream>>>(w_dg, w_dp, w_eg, w_ep, w_lo, w_og,
                                  (unsigned short*)frag);
  k_hist<<<NP / 256, 256, 0, stream>>>(ee, hist);
  k_scan<<<1, 1024, 0, stream>>>(hist, start);
  k_scatter<<<NP / 256, 256, 0, stream>>>(ee, start, hist, perm);
  k_edge2_mfma<<<NE / 64, 256, 0, stream>>>(src_ef, g_src, bt_src, wf_e2, b_eg, b_ep, e2);
  k_pairfeat<0><<<NP / 128, 256, 0, stream>>>(ee, src_ei, dst_ei, nlb, nrb, trans,
                                              wf_pair, b_dg, b_dp, feat);
  k_segsum<<<NE, 64, 0, stream>>>(start, perm, feat, e2, 0);
  k_pairfeat<1><<<NP / 128, 256, 0, stream>>>(ee, src_ei, dst_ei, nlb, nrb, trans,
                                              wf_pair, b_dg, b_dp, feat);
  k_segsum<<<NE, 64, 0, stream>>>(start, perm, feat, e2, 1);
  k_final_mfma<<<NE / 64, 256, 0, stream>>>(e2, dst_ef, g_out, bt_out, g_dst, bt_dst,
                                            wf_fin, b_lo, b_og);
}